// Round 7
// baseline (1146.436 us; speedup 1.0000x reference)
//
#include <hip/hip_runtime.h>
#include <stdint.h>

#define NODES 60000
#define NPAD  60032   // 469 * 128
#define EDGES 240000
#define KDIM  768
#define HF    768     // HEADS * F_OUT
#define FOUT  128

typedef unsigned short u16;
typedef __bf16 bf16x8 __attribute__((ext_vector_type(8)));
typedef float f32x4 __attribute__((ext_vector_type(4)));
typedef unsigned short u16x8 __attribute__((ext_vector_type(8)));

__device__ __forceinline__ float bf2f(u16 u) {
  union { uint32_t i; float f; } v; v.i = ((uint32_t)u) << 16; return v.f;
}
__device__ __forceinline__ u16 f2bf(float f) {
  union { float f; uint32_t i; } v; v.f = f;
  return (u16)((v.i + 0x7FFF + ((v.i >> 16) & 1)) >> 16);
}

// ---------------- convert x (f32 -> bf16, zero pad rows) ----------------
__global__ __launch_bounds__(256) void convert_x_k(const float* __restrict__ x, u16* __restrict__ xb) {
  const size_t g = ((size_t)blockIdx.x * 256 + threadIdx.x) * 4;
  if (g >= (size_t)NPAD * KDIM) return;
  ushort4 o;
  if (g < (size_t)NODES * KDIM) {
    const float4 v = *(const float4*)(x + g);
    o.x = f2bf(v.x); o.y = f2bf(v.y); o.z = f2bf(v.z); o.w = f2bf(v.w);
  } else { o.x = o.y = o.z = o.w = 0; }
  *(ushort4*)(xb + g) = o;
}

// ---------------- weight prep (LDS-tiled transpose) ----------------
// MODE 0: WT[n][k] = [W | skip][k][n], n<1536
// MODE 1: WT[n][k] = n<768 ? W[k][n] : mean_h skip[k][h*128 + (n-768)], n<896
template <int MODE>
__global__ __launch_bounds__(256) void prep_wcat_k(const float* __restrict__ W, const float* __restrict__ SK,
                                                   u16* __restrict__ WT) {
  __shared__ u16 tile[32][33];
  const int n0 = blockIdx.x * 32, k0 = blockIdx.y * 32;
  const int tx = threadIdx.x & 31, ty = threadIdx.x >> 5;  // 32 x 8
#pragma unroll
  for (int r = 0; r < 32; r += 8) {
    const int k = k0 + ty + r, n = n0 + tx;
    float v;
    if (n < HF) {
      v = W[(size_t)k * HF + n];
    } else if (MODE == 0) {
      v = SK[(size_t)k * HF + (n - HF)];
    } else {
      const int f = n - HF;
      v = 0.f;
#pragma unroll
      for (int h = 0; h < 6; ++h) v += SK[(size_t)k * HF + h * FOUT + f];
      v *= (1.0f / 6.0f);
    }
    tile[ty + r][tx] = f2bf(v);
  }
  __syncthreads();
#pragma unroll
  for (int r = 0; r < 32; r += 8) {
    const int n = n0 + ty + r, k = k0 + tx;
    WT[(size_t)n * KDIM + k] = tile[tx][ty + r];
  }
}

// ---------------- CSR build ----------------
__global__ __launch_bounds__(256) void hist_k(const int* __restrict__ tgt, int* __restrict__ deg) {
  const int e = blockIdx.x * 256 + threadIdx.x;
  if (e < EDGES) atomicAdd(&deg[tgt[e]], 1);
}

// thread-coarsened single-block scan: 1024 threads x 59 elems
__global__ __launch_bounds__(1024) void scan_k(int* __restrict__ degcur, int* __restrict__ rp) {
  __shared__ int ps[1024];
  const int tid = threadIdx.x;
  const int b = tid * 59;
  int s = 0;
#pragma unroll 4
  for (int i = 0; i < 59; ++i) {
    const int idx = b + i;
    if (idx < NODES) s += degcur[idx];
  }
  ps[tid] = s;
  __syncthreads();
  for (int off = 1; off < 1024; off <<= 1) {
    const int v = (tid >= off) ? ps[tid - off] : 0;
    __syncthreads();
    ps[tid] += v;
    __syncthreads();
  }
  int excl = ps[tid] - s;
  for (int i = 0; i < 59; ++i) {
    const int idx = b + i;
    if (idx < NODES) {
      const int d = degcur[idx];
      rp[idx] = excl;
      degcur[idx] = excl;
      excl += d;
    }
  }
  if (tid == 1023) rp[NODES] = excl;
}

__global__ __launch_bounds__(256) void scatter_k(const int* __restrict__ srcv, const int* __restrict__ tgt,
                                                 int* __restrict__ cur, int* __restrict__ esrc) {
  const int e = blockIdx.x * 256 + threadIdx.x;
  if (e < EDGES) {
    const int t = tgt[e];
    const int pos = atomicAdd(&cur[t], 1);
    esrc[pos] = srcv[e];
  }
}

// ---------------- per-target softmax: alpha = exp(sc - max); denom deferred ----------------
__global__ __launch_bounds__(256) void attn_k(const int* __restrict__ rp, const int* __restrict__ esrc,
                                              const float* __restrict__ ss, const float* __restrict__ stg,
                                              float* __restrict__ alp, float* __restrict__ invd) {
  const int t = blockIdx.x * 256 + threadIdx.x;
  if (t >= NODES) return;
  const int b = rp[t], e = rp[t + 1];
  float sth[6], m[6], d[6];
#pragma unroll
  for (int h = 0; h < 6; ++h) { sth[h] = stg[t * 6 + h]; m[h] = -1e30f; d[h] = 0.f; }
  for (int j = b; j < e; ++j) {
    const int s = esrc[j];
#pragma unroll
    for (int h = 0; h < 6; ++h) {
      float sc = ss[s * 6 + h] + sth[h];
      sc = sc > 0.f ? sc : 0.2f * sc;
      m[h] = fmaxf(m[h], sc);
    }
  }
  for (int j = b; j < e; ++j) {
    const int s = esrc[j];
#pragma unroll
    for (int h = 0; h < 6; ++h) {
      float sc = ss[s * 6 + h] + sth[h];
      sc = sc > 0.f ? sc : 0.2f * sc;
      const float ev = expf(sc - m[h]);
      d[h] += ev;
      alp[(size_t)j * 6 + h] = ev;
    }
  }
#pragma unroll
  for (int h = 0; h < 6; ++h) invd[t * 6 + h] = 1.f / (d[h] + 1e-16f);
}

// ---------------- bf16 MFMA GEMM + fused attention-score epilogue (R4-proven) ----------------
__global__ __launch_bounds__(256, 4) void gemm_k(const u16* __restrict__ A, const u16* __restrict__ BT,
                                                 u16* __restrict__ C,
                                                 const float* __restrict__ a_src, const float* __restrict__ a_tgt,
                                                 float* __restrict__ ss, float* __restrict__ stg,
                                                 int nbx, int ncat) {
  __shared__ u16 As[2][4096];
  __shared__ u16 Bs[2][4096];
  float* sp = (float*)&As[0][0];
  const int tid = threadIdx.x;
  const int lane = tid & 63;
  const int w = tid >> 6;
  const int wm = w >> 1, wn = w & 1;
  const int r16 = lane & 15, g4 = lane >> 4;

  const int NWG = nbx * 469;
  const int q = NWG >> 3, rr = NWG & 7;
  const int orig = blockIdx.x;
  const int xcd = orig & 7, idx = orig >> 3;
  const int wg = (xcd < rr ? xcd * (q + 1) : rr * (q + 1) + (xcd - rr) * q) + idx;
  const int bx = wg % nbx, by = wg / nbx;

  const size_t rowBase = (size_t)by * 128;
  const int colBase = bx * 128;

  const int c0 = tid, c1 = tid + 256;
  const size_t aoff0 = (rowBase + (c0 >> 2)) * KDIM + (c0 & 3) * 8;
  const size_t aoff1 = (rowBase + (c1 >> 2)) * KDIM + (c1 & 3) * 8;
  const size_t boff0 = ((size_t)(colBase + (c0 >> 2))) * KDIM + (c0 & 3) * 8;
  const size_t boff1 = ((size_t)(colBase + (c1 >> 2))) * KDIM + (c1 & 3) * 8;

  auto stage = [&](int buf, int k0) {
    __builtin_amdgcn_global_load_lds((__attribute__((address_space(1))) void*)(A + aoff0 + k0),
                                     (__attribute__((address_space(3))) void*)(&As[buf][w * 512]), 16, 0, 0);
    __builtin_amdgcn_global_load_lds((__attribute__((address_space(1))) void*)(A + aoff1 + k0),
                                     (__attribute__((address_space(3))) void*)(&As[buf][2048 + w * 512]), 16, 0, 0);
    __builtin_amdgcn_global_load_lds((__attribute__((address_space(1))) void*)(BT + boff0 + k0),
                                     (__attribute__((address_space(3))) void*)(&Bs[buf][w * 512]), 16, 0, 0);
    __builtin_amdgcn_global_load_lds((__attribute__((address_space(1))) void*)(BT + boff1 + k0),
                                     (__attribute__((address_space(3))) void*)(&Bs[buf][2048 + w * 512]), 16, 0, 0);
  };

  f32x4 acc[4][4];
#pragma unroll
  for (int i = 0; i < 4; ++i)
#pragma unroll
    for (int j = 0; j < 4; ++j) acc[i][j] = f32x4{0.f, 0.f, 0.f, 0.f};

  stage(0, 0);
  __syncthreads();
  for (int ks = 0; ks < 24; ++ks) {
    const int buf = ks & 1;
    if (ks < 23) stage(buf ^ 1, (ks + 1) * 32);
    bf16x8 af[4], bv[4];
#pragma unroll
    for (int i = 0; i < 4; ++i)
      af[i] = *(const bf16x8*)(&As[buf][(wm * 64 + i * 16 + r16) * 32 + g4 * 8]);
#pragma unroll
    for (int j = 0; j < 4; ++j)
      bv[j] = *(const bf16x8*)(&Bs[buf][(wn * 64 + j * 16 + r16) * 32 + g4 * 8]);
#pragma unroll
    for (int i = 0; i < 4; ++i)
#pragma unroll
      for (int j = 0; j < 4; ++j)
        acc[i][j] = __builtin_amdgcn_mfma_f32_16x16x32_bf16(af[i], bv[j], acc[i][j], 0, 0, 0);
    __syncthreads();
  }

#pragma unroll
  for (int i = 0; i < 4; ++i) {
    const size_t row0 = rowBase + wm * 64 + i * 16 + g4 * 4;
#pragma unroll
    for (int j = 0; j < 4; ++j) {
      const int col = colBase + wn * 64 + j * 16 + r16;
#pragma unroll
      for (int r = 0; r < 4; ++r)
        C[(row0 + r) * ncat + col] = f2bf(acc[i][j][r]);
    }
  }

  if (bx < 6) {
#pragma unroll
    for (int pass = 0; pass < 2; ++pass) {
      const float* av = (pass == 0) ? a_src : a_tgt;
      float a4[4];
#pragma unroll
      for (int j = 0; j < 4; ++j) a4[j] = av[bx * FOUT + wn * 64 + j * 16 + r16];
#pragma unroll
      for (int i = 0; i < 4; ++i) {
#pragma unroll
        for (int r = 0; r < 4; ++r) {
          float p = 0.f;
#pragma unroll
          for (int j = 0; j < 4; ++j) p += acc[i][j][r] * a4[j];
#pragma unroll
          for (int off = 1; off < 16; off <<= 1) p += __shfl_xor(p, off, 64);
          if (r16 == 0) {
            const int row = wm * 64 + i * 16 + g4 * 4 + r;
            sp[pass * 256 + wn * 128 + row] = p;
          }
        }
      }
    }
    __syncthreads();
    if (tid < 128) {
      const size_t row = rowBase + tid;
      if (row < NODES) {
        ss[row * 6 + bx] = sp[tid] + sp[128 + tid];
        stg[row * 6 + bx] = sp[256 + tid] + sp[384 + tid];
      }
    }
  }
}

// ---------------- aggregation: HALF-wave per node, ushort8 (16B) loads, deferred denom ----------------
// lane2 (<32) covers cols {lane2*8 + 256k + c : k<3, c<8}; head(col) = (lane2>>4) + 2k
template <int MODE>
__global__ __launch_bounds__(256) void aggregate_k(const u16* __restrict__ Cb, const int* __restrict__ rp,
                                                   const int* __restrict__ esrc, const float* __restrict__ alp,
                                                   const float* __restrict__ invd, const float* __restrict__ bias,
                                                   u16* __restrict__ xnext, float* __restrict__ outf) {
  constexpr int ncat = (MODE == 0) ? 1536 : 896;
  const int t = blockIdx.x * 8 + (threadIdx.x >> 5);
  const int lane2 = threadIdx.x & 31;
  if (t >= NODES) return;
  const int cbase = lane2 * 8;
  const int hsel = lane2 >> 4;
  float macc[3][8];
#pragma unroll
  for (int k = 0; k < 3; ++k)
#pragma unroll
    for (int c = 0; c < 8; ++c) macc[k][c] = 0.f;

  const int b = rp[t], e = rp[t + 1];
  int j = b;
  for (; j + 1 < e; j += 2) {
    const int s0 = esrc[j], s1 = esrc[j + 1];
    const float2 p0 = *(const float2*)(alp + (size_t)j * 6);
    const float2 p1 = *(const float2*)(alp + (size_t)j * 6 + 2);
    const float2 p2 = *(const float2*)(alp + (size_t)j * 6 + 4);
    const float2 q0 = *(const float2*)(alp + (size_t)(j + 1) * 6);
    const float2 q1 = *(const float2*)(alp + (size_t)(j + 1) * 6 + 2);
    const float2 q2 = *(const float2*)(alp + (size_t)(j + 1) * 6 + 4);
    const float a0[6] = {p0.x, p0.y, p1.x, p1.y, p2.x, p2.y};
    const float a1[6] = {q0.x, q0.y, q1.x, q1.y, q2.x, q2.y};
    const u16* pr0 = Cb + (size_t)s0 * ncat;
    const u16* pr1 = Cb + (size_t)s1 * ncat;
#pragma unroll
    for (int k = 0; k < 3; ++k) {
      const u16x8 v0 = *(const u16x8*)(pr0 + cbase + 256 * k);
      const u16x8 v1 = *(const u16x8*)(pr1 + cbase + 256 * k);
      const float aa0 = a0[hsel + 2 * k], aa1 = a1[hsel + 2 * k];
#pragma unroll
      for (int c = 0; c < 8; ++c)
        macc[k][c] += aa0 * bf2f(v0[c]) + aa1 * bf2f(v1[c]);
    }
  }
  if (j < e) {
    const int s0 = esrc[j];
    const float2 p0 = *(const float2*)(alp + (size_t)j * 6);
    const float2 p1 = *(const float2*)(alp + (size_t)j * 6 + 2);
    const float2 p2 = *(const float2*)(alp + (size_t)j * 6 + 4);
    const float a0[6] = {p0.x, p0.y, p1.x, p1.y, p2.x, p2.y};
    const u16* pr0 = Cb + (size_t)s0 * ncat;
#pragma unroll
    for (int k = 0; k < 3; ++k) {
      const u16x8 v0 = *(const u16x8*)(pr0 + cbase + 256 * k);
      const float aa0 = a0[hsel + 2 * k];
#pragma unroll
      for (int c = 0; c < 8; ++c)
        macc[k][c] += aa0 * bf2f(v0[c]);
    }
  }

  float inv[3];
#pragma unroll
  for (int k = 0; k < 3; ++k) inv[k] = invd[t * 6 + hsel + 2 * k];

  if (MODE == 0) {
    const u16* sk = Cb + (size_t)t * ncat + HF;
#pragma unroll
    for (int k = 0; k < 3; ++k) {
      const u16x8 s8 = *(const u16x8*)(sk + cbase + 256 * k);
      u16x8 o;
#pragma unroll
      for (int c = 0; c < 8; ++c) {
        float v = macc[k][c] * inv[k] + bf2f(s8[c]) + bias[cbase + 256 * k + c];
        o[c] = f2bf(v > 0.f ? v : expm1f(v));
      }
      *(u16x8*)(xnext + (size_t)t * HF + cbase + 256 * k) = o;
    }
  } else {
    float o[8];
#pragma unroll
    for (int c = 0; c < 8; ++c) {
      const float s3 = macc[0][c] * inv[0] + macc[1][c] * inv[1] + macc[2][c] * inv[2];
      o[c] = (s3 + __shfl_xor(s3, 16, 64)) * (1.0f / 6.0f);
    }
    if (hsel == 0) {
      const int f = cbase;  // lane2 < 16 -> f = lane2*8 in [0,128)
      const u16x8 s8 = *(const u16x8*)(Cb + (size_t)t * ncat + HF + f);
      float4 o0, o1;
      o0.x = o[0] + bf2f(s8[0]) + bias[f + 0];
      o0.y = o[1] + bf2f(s8[1]) + bias[f + 1];
      o0.z = o[2] + bf2f(s8[2]) + bias[f + 2];
      o0.w = o[3] + bf2f(s8[3]) + bias[f + 3];
      o1.x = o[4] + bf2f(s8[4]) + bias[f + 4];
      o1.y = o[5] + bf2f(s8[5]) + bias[f + 5];
      o1.z = o[6] + bf2f(s8[6]) + bias[f + 6];
      o1.w = o[7] + bf2f(s8[7]) + bias[f + 7];
      *(float4*)(outf + (size_t)t * FOUT + f) = o0;
      *(float4*)(outf + (size_t)t * FOUT + f + 4) = o1;
    }
  }
}

// ---------------- workspace layout ----------------
#define OFF_XBF 0ull
#define OFF_CB  92209152ull
#define OFF_WT  276627456ull   // invd aliases this region between attn and aggregate
#define OFF_SS  279023616ull
#define OFF_ST  280463616ull
#define OFF_ALP 281903616ull
#define OFF_RP  287663616ull
#define OFF_CUR 287903744ull
#define OFF_ESR 288143872ull

extern "C" void kernel_launch(void* const* d_in, const int* in_sizes, int n_in,
                              void* d_out, int out_size, void* d_ws, size_t ws_size,
                              hipStream_t stream) {
  const float* x = (const float*)d_in[0];
  const int ei = (in_sizes[1] == 2 * EDGES) ? 1 : 16;
  const int base = (ei == 1) ? 2 : 1;
  const float *W[3], *AS[3], *AT[3], *SK[3], *B[3];
  for (int l = 0; l < 3; ++l) {
    W[l]  = (const float*)d_in[base + 5 * l + 0];
    AS[l] = (const float*)d_in[base + 5 * l + 1];
    AT[l] = (const float*)d_in[base + 5 * l + 2];
    SK[l] = (const float*)d_in[base + 5 * l + 3];
    B[l]  = (const float*)d_in[base + 5 * l + 4];
  }
  const int* edges = (const int*)d_in[ei];
  const int* srcv = edges;
  const int* tgtv = edges + EDGES;
  float* out = (float*)d_out;

  char* ws = (char*)d_ws;
  u16* xbf = (u16*)(ws + OFF_XBF);
  u16* Cb  = (u16*)(ws + OFF_CB);
  u16* WT  = (u16*)(ws + OFF_WT);
  float* invd = (float*)(ws + OFF_WT);   // aliases WT: live only between attn_k and aggregate_k
  float* ss  = (float*)(ws + OFF_SS);
  float* stg = (float*)(ws + OFF_ST);
  float* alp = (float*)(ws + OFF_ALP);
  int* rp  = (int*)(ws + OFF_RP);
  int* cur = (int*)(ws + OFF_CUR);
  int* esr = (int*)(ws + OFF_ESR);

  // CSR build
  hipMemsetAsync(cur, 0, NODES * sizeof(int), stream);
  hist_k<<<(EDGES + 255) / 256, 256, 0, stream>>>(tgtv, cur);
  scan_k<<<1, 1024, 0, stream>>>(cur, rp);
  scatter_k<<<(EDGES + 255) / 256, 256, 0, stream>>>(srcv, tgtv, cur, esr);

  convert_x_k<<<45024, 256, 0, stream>>>(x, xbf);

  for (int l = 0; l < 3; ++l) {
    const int nbx = (l < 2) ? 12 : 7;
    const int ncat = nbx * 128;
    if (l < 2)
      prep_wcat_k<0><<<dim3(48, 24), 256, 0, stream>>>(W[l], SK[l], WT);
    else
      prep_wcat_k<1><<<dim3(28, 24), 256, 0, stream>>>(W[l], SK[l], WT);
    gemm_k<<<nbx * 469, 256, 0, stream>>>(xbf, WT, Cb, AS[l], AT[l], ss, stg, nbx, ncat);
    attn_k<<<(NODES + 255) / 256, 256, 0, stream>>>(rp, esr, ss, stg, alp, invd);
    if (l < 2)
      aggregate_k<0><<<7500, 256, 0, stream>>>(Cb, rp, esr, alp, invd, B[l], xbf, nullptr);
    else
      aggregate_k<1><<<7500, 256, 0, stream>>>(Cb, rp, esr, alp, invd, B[l], nullptr, out);
  }
}

// Round 8
// 903.820 us; speedup vs baseline: 1.2684x; 1.2684x over previous
//
#include <hip/hip_runtime.h>
#include <stdint.h>

#define NODES 60000
#define NPAD  60032   // 469 * 128
#define EDGES 240000
#define KDIM  768
#define HF    768     // HEADS * F_OUT
#define FOUT  128
#define SCAN_B 59     // ceil(NODES/1024)

typedef unsigned short u16;
typedef __bf16 bf16x8 __attribute__((ext_vector_type(8)));
typedef float f32x4 __attribute__((ext_vector_type(4)));

__device__ __forceinline__ float bf2f(u16 u) {
  union { uint32_t i; float f; } v; v.i = ((uint32_t)u) << 16; return v.f;
}
__device__ __forceinline__ u16 f2bf(float f) {
  union { float f; uint32_t i; } v; v.f = f;
  return (u16)((v.i + 0x7FFF + ((v.i >> 16) & 1)) >> 16);
}

// ---------------- convert x (f32 -> bf16, zero pad rows) ----------------
__global__ __launch_bounds__(256) void convert_x_k(const float* __restrict__ x, u16* __restrict__ xb) {
  const size_t g = ((size_t)blockIdx.x * 256 + threadIdx.x) * 4;
  if (g >= (size_t)NPAD * KDIM) return;
  ushort4 o;
  if (g < (size_t)NODES * KDIM) {
    const float4 v = *(const float4*)(x + g);
    o.x = f2bf(v.x); o.y = f2bf(v.y); o.z = f2bf(v.z); o.w = f2bf(v.w);
  } else { o.x = o.y = o.z = o.w = 0; }
  *(ushort4*)(xb + g) = o;
}

// ---------------- weight prep (LDS-tiled transpose) ----------------
// MODE 0: WT[n][k] = [W | skip][k][n], n<1536
// MODE 1: WT[n][k] = n<768 ? W[k][n] : mean_h skip[k][h*128 + (n-768)], n<896
template <int MODE>
__global__ __launch_bounds__(256) void prep_wcat_k(const float* __restrict__ W, const float* __restrict__ SK,
                                                   u16* __restrict__ WT) {
  __shared__ u16 tile[32][33];
  const int n0 = blockIdx.x * 32, k0 = blockIdx.y * 32;
  const int tx = threadIdx.x & 31, ty = threadIdx.x >> 5;  // 32 x 8
#pragma unroll
  for (int r = 0; r < 32; r += 8) {
    const int k = k0 + ty + r, n = n0 + tx;
    float v;
    if (n < HF) {
      v = W[(size_t)k * HF + n];
    } else if (MODE == 0) {
      v = SK[(size_t)k * HF + (n - HF)];
    } else {
      const int f = n - HF;
      v = 0.f;
#pragma unroll
      for (int h = 0; h < 6; ++h) v += SK[(size_t)k * HF + h * FOUT + f];
      v *= (1.0f / 6.0f);
    }
    tile[ty + r][tx] = f2bf(v);
  }
  __syncthreads();
#pragma unroll
  for (int r = 0; r < 32; r += 8) {
    const int n = n0 + ty + r, k = k0 + tx;
    WT[(size_t)n * KDIM + k] = tile[tx][ty + r];
  }
}

// ---------------- CSR build ----------------
__global__ __launch_bounds__(256) void hist_k(const int* __restrict__ tgt, int* __restrict__ deg) {
  const int e = blockIdx.x * 256 + threadIdx.x;
  if (e < EDGES) atomicAdd(&deg[tgt[e]], 1);
}

// 3-kernel coalesced scan: per-block Hillis-Steele -> scan block totals -> add offsets
__global__ __launch_bounds__(1024) void scan1_k(const int* __restrict__ deg, int* __restrict__ rp,
                                                int* __restrict__ partial) {
  __shared__ int buf[1024];
  const int tid = threadIdx.x;
  const int i = blockIdx.x * 1024 + tid;
  const int v = (i < NODES) ? deg[i] : 0;
  buf[tid] = v;
  __syncthreads();
  for (int off = 1; off < 1024; off <<= 1) {
    const int t = (tid >= off) ? buf[tid - off] : 0;
    __syncthreads();
    buf[tid] += t;
    __syncthreads();
  }
  if (i < NODES) rp[i] = buf[tid] - v;  // local exclusive
  if (tid == 1023) partial[blockIdx.x] = buf[1023];
}

__global__ __launch_bounds__(64) void scan2_k(int* __restrict__ partial, int* __restrict__ rpN) {
  __shared__ int buf[64];
  const int tid = threadIdx.x;
  const int v = (tid < SCAN_B) ? partial[tid] : 0;
  buf[tid] = v;
  __syncthreads();
  for (int off = 1; off < 64; off <<= 1) {
    const int t = (tid >= off) ? buf[tid - off] : 0;
    __syncthreads();
    buf[tid] += t;
    __syncthreads();
  }
  if (tid < SCAN_B) partial[tid] = buf[tid] - v;  // exclusive block offsets
  if (tid == 63) *rpN = buf[63];                  // total edge count
}

__global__ __launch_bounds__(1024) void scan3_k(int* __restrict__ rp, const int* __restrict__ partial,
                                                int* __restrict__ cur) {
  const int i = blockIdx.x * 1024 + threadIdx.x;
  if (i < NODES) {
    const int v = rp[i] + partial[blockIdx.x];
    rp[i] = v;
    cur[i] = v;
  }
}

__global__ __launch_bounds__(256) void scatter_k(const int* __restrict__ srcv, const int* __restrict__ tgt,
                                                 int* __restrict__ cur, int* __restrict__ esrc) {
  const int e = blockIdx.x * 256 + threadIdx.x;
  if (e < EDGES) {
    const int t = tgt[e];
    const int pos = atomicAdd(&cur[t], 1);
    esrc[pos] = srcv[e];
  }
}

// ---------------- per-target softmax: alpha = exp(sc - max); denom deferred ----------------
__global__ __launch_bounds__(256) void attn_k(const int* __restrict__ rp, const int* __restrict__ esrc,
                                              const float* __restrict__ ss, const float* __restrict__ stg,
                                              float* __restrict__ alp, float* __restrict__ invd) {
  const int t = blockIdx.x * 256 + threadIdx.x;
  if (t >= NODES) return;
  const int b = rp[t], e = rp[t + 1];
  float sth[6], m[6], d[6];
#pragma unroll
  for (int h = 0; h < 6; ++h) { sth[h] = stg[t * 6 + h]; m[h] = -1e30f; d[h] = 0.f; }
  for (int j = b; j < e; ++j) {
    const int s = esrc[j];
#pragma unroll
    for (int h = 0; h < 6; ++h) {
      float sc = ss[s * 6 + h] + sth[h];
      sc = sc > 0.f ? sc : 0.2f * sc;
      m[h] = fmaxf(m[h], sc);
    }
  }
  for (int j = b; j < e; ++j) {
    const int s = esrc[j];
#pragma unroll
    for (int h = 0; h < 6; ++h) {
      float sc = ss[s * 6 + h] + sth[h];
      sc = sc > 0.f ? sc : 0.2f * sc;
      const float ev = expf(sc - m[h]);
      d[h] += ev;
      alp[(size_t)j * 6 + h] = ev;
    }
  }
#pragma unroll
  for (int h = 0; h < 6; ++h) invd[t * 6 + h] = 1.f / (d[h] + 1e-16f);
}

// ---------------- bf16 MFMA GEMM + fused attention-score epilogue (R4-proven) ----------------
__global__ __launch_bounds__(256, 4) void gemm_k(const u16* __restrict__ A, const u16* __restrict__ BT,
                                                 u16* __restrict__ C,
                                                 const float* __restrict__ a_src, const float* __restrict__ a_tgt,
                                                 float* __restrict__ ss, float* __restrict__ stg,
                                                 int nbx, int ncat) {
  __shared__ u16 As[2][4096];
  __shared__ u16 Bs[2][4096];
  float* sp = (float*)&As[0][0];
  const int tid = threadIdx.x;
  const int lane = tid & 63;
  const int w = tid >> 6;
  const int wm = w >> 1, wn = w & 1;
  const int r16 = lane & 15, g4 = lane >> 4;

  const int NWG = nbx * 469;
  const int q = NWG >> 3, rr = NWG & 7;
  const int orig = blockIdx.x;
  const int xcd = orig & 7, idx = orig >> 3;
  const int wg = (xcd < rr ? xcd * (q + 1) : rr * (q + 1) + (xcd - rr) * q) + idx;
  const int bx = wg % nbx, by = wg / nbx;

  const size_t rowBase = (size_t)by * 128;
  const int colBase = bx * 128;

  const int c0 = tid, c1 = tid + 256;
  const size_t aoff0 = (rowBase + (c0 >> 2)) * KDIM + (c0 & 3) * 8;
  const size_t aoff1 = (rowBase + (c1 >> 2)) * KDIM + (c1 & 3) * 8;
  const size_t boff0 = ((size_t)(colBase + (c0 >> 2))) * KDIM + (c0 & 3) * 8;
  const size_t boff1 = ((size_t)(colBase + (c1 >> 2))) * KDIM + (c1 & 3) * 8;

  auto stage = [&](int buf, int k0) {
    __builtin_amdgcn_global_load_lds((__attribute__((address_space(1))) void*)(A + aoff0 + k0),
                                     (__attribute__((address_space(3))) void*)(&As[buf][w * 512]), 16, 0, 0);
    __builtin_amdgcn_global_load_lds((__attribute__((address_space(1))) void*)(A + aoff1 + k0),
                                     (__attribute__((address_space(3))) void*)(&As[buf][2048 + w * 512]), 16, 0, 0);
    __builtin_amdgcn_global_load_lds((__attribute__((address_space(1))) void*)(BT + boff0 + k0),
                                     (__attribute__((address_space(3))) void*)(&Bs[buf][w * 512]), 16, 0, 0);
    __builtin_amdgcn_global_load_lds((__attribute__((address_space(1))) void*)(BT + boff1 + k0),
                                     (__attribute__((address_space(3))) void*)(&Bs[buf][2048 + w * 512]), 16, 0, 0);
  };

  f32x4 acc[4][4];
#pragma unroll
  for (int i = 0; i < 4; ++i)
#pragma unroll
    for (int j = 0; j < 4; ++j) acc[i][j] = f32x4{0.f, 0.f, 0.f, 0.f};

  stage(0, 0);
  __syncthreads();
  for (int ks = 0; ks < 24; ++ks) {
    const int buf = ks & 1;
    if (ks < 23) stage(buf ^ 1, (ks + 1) * 32);
    bf16x8 af[4], bv[4];
#pragma unroll
    for (int i = 0; i < 4; ++i)
      af[i] = *(const bf16x8*)(&As[buf][(wm * 64 + i * 16 + r16) * 32 + g4 * 8]);
#pragma unroll
    for (int j = 0; j < 4; ++j)
      bv[j] = *(const bf16x8*)(&Bs[buf][(wn * 64 + j * 16 + r16) * 32 + g4 * 8]);
#pragma unroll
    for (int i = 0; i < 4; ++i)
#pragma unroll
      for (int j = 0; j < 4; ++j)
        acc[i][j] = __builtin_amdgcn_mfma_f32_16x16x32_bf16(af[i], bv[j], acc[i][j], 0, 0, 0);
    __syncthreads();
  }

#pragma unroll
  for (int i = 0; i < 4; ++i) {
    const size_t row0 = rowBase + wm * 64 + i * 16 + g4 * 4;
#pragma unroll
    for (int j = 0; j < 4; ++j) {
      const int col = colBase + wn * 64 + j * 16 + r16;
#pragma unroll
      for (int r = 0; r < 4; ++r)
        C[(row0 + r) * ncat + col] = f2bf(acc[i][j][r]);
    }
  }

  if (bx < 6) {
#pragma unroll
    for (int pass = 0; pass < 2; ++pass) {
      const float* av = (pass == 0) ? a_src : a_tgt;
      float a4[4];
#pragma unroll
      for (int j = 0; j < 4; ++j) a4[j] = av[bx * FOUT + wn * 64 + j * 16 + r16];
#pragma unroll
      for (int i = 0; i < 4; ++i) {
#pragma unroll
        for (int r = 0; r < 4; ++r) {
          float p = 0.f;
#pragma unroll
          for (int j = 0; j < 4; ++j) p += acc[i][j][r] * a4[j];
#pragma unroll
          for (int off = 1; off < 16; off <<= 1) p += __shfl_xor(p, off, 64);
          if (r16 == 0) {
            const int row = wm * 64 + i * 16 + g4 * 4 + r;
            sp[pass * 256 + wn * 128 + row] = p;
          }
        }
      }
    }
    __syncthreads();
    if (tid < 128) {
      const size_t row = rowBase + tid;
      if (row < NODES) {
        ss[row * 6 + bx] = sp[tid] + sp[128 + tid];
        stg[row * 6 + bx] = sp[256 + tid] + sp[384 + tid];
      }
    }
  }
}

// ---------------- aggregation: one wave per target node, vectorized, deferred denom (R4-proven) ----------------
// lane covers cols {lane*4 + 256k + c : k<3, c<4}; head(col) = (lane>>5) + 2k
template <int MODE>
__global__ __launch_bounds__(256) void aggregate_k(const u16* __restrict__ Cb, const int* __restrict__ rp,
                                                   const int* __restrict__ esrc, const float* __restrict__ alp,
                                                   const float* __restrict__ invd, const float* __restrict__ bias,
                                                   u16* __restrict__ xnext, float* __restrict__ outf) {
  constexpr int ncat = (MODE == 0) ? 1536 : 896;
  const int t = blockIdx.x * 4 + (threadIdx.x >> 6);
  const int lane = threadIdx.x & 63;
  if (t >= NODES) return;
  const int l4 = lane * 4;
  const int h0 = lane >> 5;
  float macc[3][4];
#pragma unroll
  for (int k = 0; k < 3; ++k)
#pragma unroll
    for (int c = 0; c < 4; ++c) macc[k][c] = 0.f;

  const int b = rp[t], e = rp[t + 1];
  int j = b;
  for (; j + 1 < e; j += 2) {
    const int s0 = esrc[j], s1 = esrc[j + 1];
    const float2 p0 = *(const float2*)(alp + (size_t)j * 6);
    const float2 p1 = *(const float2*)(alp + (size_t)j * 6 + 2);
    const float2 p2 = *(const float2*)(alp + (size_t)j * 6 + 4);
    const float2 q0 = *(const float2*)(alp + (size_t)(j + 1) * 6);
    const float2 q1 = *(const float2*)(alp + (size_t)(j + 1) * 6 + 2);
    const float2 q2 = *(const float2*)(alp + (size_t)(j + 1) * 6 + 4);
    const float a0[6] = {p0.x, p0.y, p1.x, p1.y, p2.x, p2.y};
    const float a1[6] = {q0.x, q0.y, q1.x, q1.y, q2.x, q2.y};
    const u16* pr0 = Cb + (size_t)s0 * ncat;
    const u16* pr1 = Cb + (size_t)s1 * ncat;
#pragma unroll
    for (int k = 0; k < 3; ++k) {
      const ushort4 v0 = *(const ushort4*)(pr0 + l4 + 256 * k);
      const ushort4 v1 = *(const ushort4*)(pr1 + l4 + 256 * k);
      const float aa0 = a0[h0 + 2 * k], aa1 = a1[h0 + 2 * k];
      macc[k][0] += aa0 * bf2f(v0.x) + aa1 * bf2f(v1.x);
      macc[k][1] += aa0 * bf2f(v0.y) + aa1 * bf2f(v1.y);
      macc[k][2] += aa0 * bf2f(v0.z) + aa1 * bf2f(v1.z);
      macc[k][3] += aa0 * bf2f(v0.w) + aa1 * bf2f(v1.w);
    }
  }
  if (j < e) {
    const int s0 = esrc[j];
    const float2 p0 = *(const float2*)(alp + (size_t)j * 6);
    const float2 p1 = *(const float2*)(alp + (size_t)j * 6 + 2);
    const float2 p2 = *(const float2*)(alp + (size_t)j * 6 + 4);
    const float a0[6] = {p0.x, p0.y, p1.x, p1.y, p2.x, p2.y};
    const u16* pr0 = Cb + (size_t)s0 * ncat;
#pragma unroll
    for (int k = 0; k < 3; ++k) {
      const ushort4 v0 = *(const ushort4*)(pr0 + l4 + 256 * k);
      const float aa0 = a0[h0 + 2 * k];
      macc[k][0] += aa0 * bf2f(v0.x);
      macc[k][1] += aa0 * bf2f(v0.y);
      macc[k][2] += aa0 * bf2f(v0.z);
      macc[k][3] += aa0 * bf2f(v0.w);
    }
  }

  float inv[3];
#pragma unroll
  for (int k = 0; k < 3; ++k) inv[k] = invd[t * 6 + h0 + 2 * k];

  if (MODE == 0) {
    const u16* sk = Cb + (size_t)t * ncat + HF;
#pragma unroll
    for (int k = 0; k < 3; ++k) {
      const ushort4 s4 = *(const ushort4*)(sk + l4 + 256 * k);
      ushort4 o;
      float v0 = macc[k][0] * inv[k] + bf2f(s4.x) + bias[l4 + 256 * k];
      float v1 = macc[k][1] * inv[k] + bf2f(s4.y) + bias[l4 + 256 * k + 1];
      float v2 = macc[k][2] * inv[k] + bf2f(s4.z) + bias[l4 + 256 * k + 2];
      float v3 = macc[k][3] * inv[k] + bf2f(s4.w) + bias[l4 + 256 * k + 3];
      o.x = f2bf(v0 > 0.f ? v0 : expm1f(v0));
      o.y = f2bf(v1 > 0.f ? v1 : expm1f(v1));
      o.z = f2bf(v2 > 0.f ? v2 : expm1f(v2));
      o.w = f2bf(v3 > 0.f ? v3 : expm1f(v3));
      *(ushort4*)(xnext + (size_t)t * HF + l4 + 256 * k) = o;
    }
  } else {
    float4 o;
    float* op = &o.x;
#pragma unroll
    for (int c = 0; c < 4; ++c) {
      const float s3 = macc[0][c] * inv[0] + macc[1][c] * inv[1] + macc[2][c] * inv[2];
      const float tot = s3 + __shfl_xor(s3, 32, 64);
      op[c] = tot * (1.0f / 6.0f);
    }
    if (lane < 32) {
      const int f = lane * 4;
      const ushort4 s4 = *(const ushort4*)(Cb + (size_t)t * ncat + HF + f);
      o.x += bf2f(s4.x) + bias[f];
      o.y += bf2f(s4.y) + bias[f + 1];
      o.z += bf2f(s4.z) + bias[f + 2];
      o.w += bf2f(s4.w) + bias[f + 3];
      *(float4*)(outf + (size_t)t * FOUT + f) = o;
    }
  }
}

// ---------------- workspace layout ----------------
#define OFF_XBF 0ull
#define OFF_CB  92209152ull
#define OFF_WT  276627456ull   // invd aliases this region between attn and aggregate; scan partials alias it during CSR build
#define OFF_SS  279023616ull
#define OFF_ST  280463616ull
#define OFF_ALP 281903616ull
#define OFF_RP  287663616ull
#define OFF_CUR 287903744ull
#define OFF_ESR 288143872ull

extern "C" void kernel_launch(void* const* d_in, const int* in_sizes, int n_in,
                              void* d_out, int out_size, void* d_ws, size_t ws_size,
                              hipStream_t stream) {
  const float* x = (const float*)d_in[0];
  const int ei = (in_sizes[1] == 2 * EDGES) ? 1 : 16;
  const int base = (ei == 1) ? 2 : 1;
  const float *W[3], *AS[3], *AT[3], *SK[3], *B[3];
  for (int l = 0; l < 3; ++l) {
    W[l]  = (const float*)d_in[base + 5 * l + 0];
    AS[l] = (const float*)d_in[base + 5 * l + 1];
    AT[l] = (const float*)d_in[base + 5 * l + 2];
    SK[l] = (const float*)d_in[base + 5 * l + 3];
    B[l]  = (const float*)d_in[base + 5 * l + 4];
  }
  const int* edges = (const int*)d_in[ei];
  const int* srcv = edges;
  const int* tgtv = edges + EDGES;
  float* out = (float*)d_out;

  char* ws = (char*)d_ws;
  u16* xbf = (u16*)(ws + OFF_XBF);
  u16* Cb  = (u16*)(ws + OFF_CB);
  u16* WT  = (u16*)(ws + OFF_WT);
  float* invd = (float*)(ws + OFF_WT);   // aliases WT: live only between attn_k and aggregate_k
  int* partial = (int*)(ws + OFF_WT);    // aliases WT: live only during CSR build (before first prep)
  float* ss  = (float*)(ws + OFF_SS);
  float* stg = (float*)(ws + OFF_ST);
  float* alp = (float*)(ws + OFF_ALP);
  int* rp  = (int*)(ws + OFF_RP);
  int* cur = (int*)(ws + OFF_CUR);
  int* esr = (int*)(ws + OFF_ESR);

  // CSR build
  hipMemsetAsync(cur, 0, NODES * sizeof(int), stream);
  hist_k<<<(EDGES + 255) / 256, 256, 0, stream>>>(tgtv, cur);
  scan1_k<<<SCAN_B, 1024, 0, stream>>>(cur, rp, partial);
  scan2_k<<<1, 64, 0, stream>>>(partial, rp + NODES);
  scan3_k<<<SCAN_B, 1024, 0, stream>>>(rp, partial, cur);
  scatter_k<<<(EDGES + 255) / 256, 256, 0, stream>>>(srcv, tgtv, cur, esr);

  convert_x_k<<<45024, 256, 0, stream>>>(x, xbf);

  for (int l = 0; l < 3; ++l) {
    const int nbx = (l < 2) ? 12 : 7;
    const int ncat = nbx * 128;
    if (l < 2)
      prep_wcat_k<0><<<dim3(48, 24), 256, 0, stream>>>(W[l], SK[l], WT);
    else
      prep_wcat_k<1><<<dim3(28, 24), 256, 0, stream>>>(W[l], SK[l], WT);
    gemm_k<<<nbx * 469, 256, 0, stream>>>(xbf, WT, Cb, AS[l], AT[l], ss, stg, nbx, ncat);
    attn_k<<<(NODES + 255) / 256, 256, 0, stream>>>(rp, esr, ss, stg, alp, invd);
    if (l < 2)
      aggregate_k<0><<<15000, 256, 0, stream>>>(Cb, rp, esr, alp, invd, B[l], xbf, nullptr);
    else
      aggregate_k<1><<<15000, 256, 0, stream>>>(Cb, rp, esr, alp, invd, B[l], nullptr, out);
  }
}

// Round 9
// 877.138 us; speedup vs baseline: 1.3070x; 1.0304x over previous
//
#include <hip/hip_runtime.h>
#include <stdint.h>

#define NODES 60000
#define NPAD  60032   // 469 * 128
#define EDGES 240000
#define KDIM  768
#define HF    768     // HEADS * F_OUT
#define FOUT  128
#define SCAN_B 59     // ceil(NODES/1024)

typedef unsigned short u16;
typedef __bf16 bf16x8 __attribute__((ext_vector_type(8)));
typedef float f32x4 __attribute__((ext_vector_type(4)));

__device__ __forceinline__ float bf2f(u16 u) {
  union { uint32_t i; float f; } v; v.i = ((uint32_t)u) << 16; return v.f;
}
__device__ __forceinline__ u16 f2bf(float f) {
  union { float f; uint32_t i; } v; v.f = f;
  return (u16)((v.i + 0x7FFF + ((v.i >> 16) & 1)) >> 16);
}

// ---------------- convert x (f32 -> bf16, zero pad rows) ----------------
__global__ __launch_bounds__(256) void convert_x_k(const float* __restrict__ x, u16* __restrict__ xb) {
  const size_t g = ((size_t)blockIdx.x * 256 + threadIdx.x) * 4;
  if (g >= (size_t)NPAD * KDIM) return;
  ushort4 o;
  if (g < (size_t)NODES * KDIM) {
    const float4 v = *(const float4*)(x + g);
    o.x = f2bf(v.x); o.y = f2bf(v.y); o.z = f2bf(v.z); o.w = f2bf(v.w);
  } else { o.x = o.y = o.z = o.w = 0; }
  *(ushort4*)(xb + g) = o;
}

// ---------------- weight prep (LDS-tiled transpose) ----------------
// MODE 0: WT[n][k] = [W | skip][k][n], n<1536
// MODE 1: WT[n][k] = n<768 ? W[k][n] : mean_h skip[k][h*128 + (n-768)], n<896
template <int MODE>
__global__ __launch_bounds__(256) void prep_wcat_k(const float* __restrict__ W, const float* __restrict__ SK,
                                                   u16* __restrict__ WT) {
  __shared__ u16 tile[32][33];
  const int n0 = blockIdx.x * 32, k0 = blockIdx.y * 32;
  const int tx = threadIdx.x & 31, ty = threadIdx.x >> 5;  // 32 x 8
#pragma unroll
  for (int r = 0; r < 32; r += 8) {
    const int k = k0 + ty + r, n = n0 + tx;
    float v;
    if (n < HF) {
      v = W[(size_t)k * HF + n];
    } else if (MODE == 0) {
      v = SK[(size_t)k * HF + (n - HF)];
    } else {
      const int f = n - HF;
      v = 0.f;
#pragma unroll
      for (int h = 0; h < 6; ++h) v += SK[(size_t)k * HF + h * FOUT + f];
      v *= (1.0f / 6.0f);
    }
    tile[ty + r][tx] = f2bf(v);
  }
  __syncthreads();
#pragma unroll
  for (int r = 0; r < 32; r += 8) {
    const int n = n0 + ty + r, k = k0 + tx;
    WT[(size_t)n * KDIM + k] = tile[tx][ty + r];
  }
}

// ---------------- CSR build ----------------
__global__ __launch_bounds__(256) void hist_k(const int* __restrict__ tgt, int* __restrict__ deg) {
  const int e = blockIdx.x * 256 + threadIdx.x;
  if (e < EDGES) atomicAdd(&deg[tgt[e]], 1);
}

// 3-kernel coalesced scan: per-block Hillis-Steele -> scan block totals -> add offsets
__global__ __launch_bounds__(1024) void scan1_k(const int* __restrict__ deg, int* __restrict__ rp,
                                                int* __restrict__ partial) {
  __shared__ int buf[1024];
  const int tid = threadIdx.x;
  const int i = blockIdx.x * 1024 + tid;
  const int v = (i < NODES) ? deg[i] : 0;
  buf[tid] = v;
  __syncthreads();
  for (int off = 1; off < 1024; off <<= 1) {
    const int t = (tid >= off) ? buf[tid - off] : 0;
    __syncthreads();
    buf[tid] += t;
    __syncthreads();
  }
  if (i < NODES) rp[i] = buf[tid] - v;  // local exclusive
  if (tid == 1023) partial[blockIdx.x] = buf[1023];
}

__global__ __launch_bounds__(64) void scan2_k(int* __restrict__ partial, int* __restrict__ rpN) {
  __shared__ int buf[64];
  const int tid = threadIdx.x;
  const int v = (tid < SCAN_B) ? partial[tid] : 0;
  buf[tid] = v;
  __syncthreads();
  for (int off = 1; off < 64; off <<= 1) {
    const int t = (tid >= off) ? buf[tid - off] : 0;
    __syncthreads();
    buf[tid] += t;
    __syncthreads();
  }
  if (tid < SCAN_B) partial[tid] = buf[tid] - v;  // exclusive block offsets
  if (tid == 63) *rpN = buf[63];                  // total edge count
}

__global__ __launch_bounds__(1024) void scan3_k(int* __restrict__ rp, const int* __restrict__ partial,
                                                int* __restrict__ cur) {
  const int i = blockIdx.x * 1024 + threadIdx.x;
  if (i < NODES) {
    const int v = rp[i] + partial[blockIdx.x];
    rp[i] = v;
    cur[i] = v;
  }
}

__global__ __launch_bounds__(256) void scatter_k(const int* __restrict__ srcv, const int* __restrict__ tgt,
                                                 int* __restrict__ cur, int* __restrict__ esrc) {
  const int e = blockIdx.x * 256 + threadIdx.x;
  if (e < EDGES) {
    const int t = tgt[e];
    const int pos = atomicAdd(&cur[t], 1);
    esrc[pos] = srcv[e];
  }
}

// ---------------- bf16 MFMA GEMM + fused attention-score epilogue (R4-proven) ----------------
__global__ __launch_bounds__(256, 4) void gemm_k(const u16* __restrict__ A, const u16* __restrict__ BT,
                                                 u16* __restrict__ C,
                                                 const float* __restrict__ a_src, const float* __restrict__ a_tgt,
                                                 float* __restrict__ ss, float* __restrict__ stg,
                                                 int nbx, int ncat) {
  __shared__ u16 As[2][4096];
  __shared__ u16 Bs[2][4096];
  float* sp = (float*)&As[0][0];
  const int tid = threadIdx.x;
  const int lane = tid & 63;
  const int w = tid >> 6;
  const int wm = w >> 1, wn = w & 1;
  const int r16 = lane & 15, g4 = lane >> 4;

  const int NWG = nbx * 469;
  const int q = NWG >> 3, rr = NWG & 7;
  const int orig = blockIdx.x;
  const int xcd = orig & 7, idx = orig >> 3;
  const int wg = (xcd < rr ? xcd * (q + 1) : rr * (q + 1) + (xcd - rr) * q) + idx;
  const int bx = wg % nbx, by = wg / nbx;

  const size_t rowBase = (size_t)by * 128;
  const int colBase = bx * 128;

  const int c0 = tid, c1 = tid + 256;
  const size_t aoff0 = (rowBase + (c0 >> 2)) * KDIM + (c0 & 3) * 8;
  const size_t aoff1 = (rowBase + (c1 >> 2)) * KDIM + (c1 & 3) * 8;
  const size_t boff0 = ((size_t)(colBase + (c0 >> 2))) * KDIM + (c0 & 3) * 8;
  const size_t boff1 = ((size_t)(colBase + (c1 >> 2))) * KDIM + (c1 & 3) * 8;

  auto stage = [&](int buf, int k0) {
    __builtin_amdgcn_global_load_lds((__attribute__((address_space(1))) void*)(A + aoff0 + k0),
                                     (__attribute__((address_space(3))) void*)(&As[buf][w * 512]), 16, 0, 0);
    __builtin_amdgcn_global_load_lds((__attribute__((address_space(1))) void*)(A + aoff1 + k0),
                                     (__attribute__((address_space(3))) void*)(&As[buf][2048 + w * 512]), 16, 0, 0);
    __builtin_amdgcn_global_load_lds((__attribute__((address_space(1))) void*)(BT + boff0 + k0),
                                     (__attribute__((address_space(3))) void*)(&Bs[buf][w * 512]), 16, 0, 0);
    __builtin_amdgcn_global_load_lds((__attribute__((address_space(1))) void*)(BT + boff1 + k0),
                                     (__attribute__((address_space(3))) void*)(&Bs[buf][2048 + w * 512]), 16, 0, 0);
  };

  f32x4 acc[4][4];
#pragma unroll
  for (int i = 0; i < 4; ++i)
#pragma unroll
    for (int j = 0; j < 4; ++j) acc[i][j] = f32x4{0.f, 0.f, 0.f, 0.f};

  stage(0, 0);
  __syncthreads();
  for (int ks = 0; ks < 24; ++ks) {
    const int buf = ks & 1;
    if (ks < 23) stage(buf ^ 1, (ks + 1) * 32);
    bf16x8 af[4], bv[4];
#pragma unroll
    for (int i = 0; i < 4; ++i)
      af[i] = *(const bf16x8*)(&As[buf][(wm * 64 + i * 16 + r16) * 32 + g4 * 8]);
#pragma unroll
    for (int j = 0; j < 4; ++j)
      bv[j] = *(const bf16x8*)(&Bs[buf][(wn * 64 + j * 16 + r16) * 32 + g4 * 8]);
#pragma unroll
    for (int i = 0; i < 4; ++i)
#pragma unroll
      for (int j = 0; j < 4; ++j)
        acc[i][j] = __builtin_amdgcn_mfma_f32_16x16x32_bf16(af[i], bv[j], acc[i][j], 0, 0, 0);
    __syncthreads();
  }

#pragma unroll
  for (int i = 0; i < 4; ++i) {
    const size_t row0 = rowBase + wm * 64 + i * 16 + g4 * 4;
#pragma unroll
    for (int j = 0; j < 4; ++j) {
      const int col = colBase + wn * 64 + j * 16 + r16;
#pragma unroll
      for (int r = 0; r < 4; ++r)
        C[(row0 + r) * ncat + col] = f2bf(acc[i][j][r]);
    }
  }

  if (bx < 6) {
#pragma unroll
    for (int pass = 0; pass < 2; ++pass) {
      const float* av = (pass == 0) ? a_src : a_tgt;
      float a4[4];
#pragma unroll
      for (int j = 0; j < 4; ++j) a4[j] = av[bx * FOUT + wn * 64 + j * 16 + r16];
#pragma unroll
      for (int i = 0; i < 4; ++i) {
#pragma unroll
        for (int r = 0; r < 4; ++r) {
          float p = 0.f;
#pragma unroll
          for (int j = 0; j < 4; ++j) p += acc[i][j][r] * a4[j];
#pragma unroll
          for (int off = 1; off < 16; off <<= 1) p += __shfl_xor(p, off, 64);
          if (r16 == 0) {
            const int row = wm * 64 + i * 16 + g4 * 4 + r;
            sp[pass * 256 + wn * 128 + row] = p;
          }
        }
      }
    }
    __syncthreads();
    if (tid < 128) {
      const size_t row = rowBase + tid;
      if (row < NODES) {
        ss[row * 6 + bx] = sp[tid] + sp[128 + tid];
        stg[row * 6 + bx] = sp[256 + tid] + sp[384 + tid];
      }
    }
  }
}

// ---------------- fused softmax + aggregation: one wave per target node ----------------
// lane covers cols {lane*4 + 256k + c : k<3, c<4}; head(col) = (lane>>5) + 2k =: hk
// pass 1: per-head max over edges; pass 2: gather proj rows, ev=exp(sc-m) inline, accumulate denom;
// epilogue: normalize, add skip+bias, activation. No alpha buffer, no separate attn kernel.
template <int MODE>
__global__ __launch_bounds__(256) void aggregate_k(const u16* __restrict__ Cb, const int* __restrict__ rp,
                                                   const int* __restrict__ esrc,
                                                   const float* __restrict__ ss, const float* __restrict__ stg,
                                                   const float* __restrict__ bias,
                                                   u16* __restrict__ xnext, float* __restrict__ outf) {
  constexpr int ncat = (MODE == 0) ? 1536 : 896;
  const int t = blockIdx.x * 4 + (threadIdx.x >> 6);
  const int lane = threadIdx.x & 63;
  if (t >= NODES) return;
  const int l4 = lane * 4;
  const int h0 = lane >> 5;

  const int b = rp[t], e = rp[t + 1];

  float sth[3], m[3];
#pragma unroll
  for (int k = 0; k < 3; ++k) { sth[k] = stg[t * 6 + h0 + 2 * k]; m[k] = -1e30f; }

  // ---- pass 1: per-head max (lrelu'd scores) ----
  int j = b;
  for (; j + 1 < e; j += 2) {
    const int s0 = esrc[j], s1 = esrc[j + 1];
#pragma unroll
    for (int k = 0; k < 3; ++k) {
      float sc0 = ss[s0 * 6 + h0 + 2 * k] + sth[k];
      float sc1 = ss[s1 * 6 + h0 + 2 * k] + sth[k];
      sc0 = sc0 > 0.f ? sc0 : 0.2f * sc0;
      sc1 = sc1 > 0.f ? sc1 : 0.2f * sc1;
      m[k] = fmaxf(m[k], fmaxf(sc0, sc1));
    }
  }
  if (j < e) {
    const int s0 = esrc[j];
#pragma unroll
    for (int k = 0; k < 3; ++k) {
      float sc0 = ss[s0 * 6 + h0 + 2 * k] + sth[k];
      sc0 = sc0 > 0.f ? sc0 : 0.2f * sc0;
      m[k] = fmaxf(m[k], sc0);
    }
  }

  // ---- pass 2: gather + exp + accumulate ----
  float macc[3][4], d[3];
#pragma unroll
  for (int k = 0; k < 3; ++k) {
    d[k] = 0.f;
#pragma unroll
    for (int c = 0; c < 4; ++c) macc[k][c] = 0.f;
  }
  j = b;
  for (; j + 1 < e; j += 2) {
    const int s0 = esrc[j], s1 = esrc[j + 1];
    const u16* pr0 = Cb + (size_t)s0 * ncat;
    const u16* pr1 = Cb + (size_t)s1 * ncat;
#pragma unroll
    for (int k = 0; k < 3; ++k) {
      const ushort4 v0 = *(const ushort4*)(pr0 + l4 + 256 * k);
      const ushort4 v1 = *(const ushort4*)(pr1 + l4 + 256 * k);
      float sc0 = ss[s0 * 6 + h0 + 2 * k] + sth[k];
      float sc1 = ss[s1 * 6 + h0 + 2 * k] + sth[k];
      sc0 = sc0 > 0.f ? sc0 : 0.2f * sc0;
      sc1 = sc1 > 0.f ? sc1 : 0.2f * sc1;
      const float ev0 = __expf(sc0 - m[k]);
      const float ev1 = __expf(sc1 - m[k]);
      d[k] += ev0 + ev1;
      macc[k][0] += ev0 * bf2f(v0.x) + ev1 * bf2f(v1.x);
      macc[k][1] += ev0 * bf2f(v0.y) + ev1 * bf2f(v1.y);
      macc[k][2] += ev0 * bf2f(v0.z) + ev1 * bf2f(v1.z);
      macc[k][3] += ev0 * bf2f(v0.w) + ev1 * bf2f(v1.w);
    }
  }
  if (j < e) {
    const int s0 = esrc[j];
    const u16* pr0 = Cb + (size_t)s0 * ncat;
#pragma unroll
    for (int k = 0; k < 3; ++k) {
      const ushort4 v0 = *(const ushort4*)(pr0 + l4 + 256 * k);
      float sc0 = ss[s0 * 6 + h0 + 2 * k] + sth[k];
      sc0 = sc0 > 0.f ? sc0 : 0.2f * sc0;
      const float ev0 = __expf(sc0 - m[k]);
      d[k] += ev0;
      macc[k][0] += ev0 * bf2f(v0.x);
      macc[k][1] += ev0 * bf2f(v0.y);
      macc[k][2] += ev0 * bf2f(v0.z);
      macc[k][3] += ev0 * bf2f(v0.w);
    }
  }

  float inv[3];
#pragma unroll
  for (int k = 0; k < 3; ++k) inv[k] = 1.f / (d[k] + 1e-16f);

  if (MODE == 0) {
    const u16* sk = Cb + (size_t)t * ncat + HF;
#pragma unroll
    for (int k = 0; k < 3; ++k) {
      const ushort4 s4 = *(const ushort4*)(sk + l4 + 256 * k);
      ushort4 o;
      float v0 = macc[k][0] * inv[k] + bf2f(s4.x) + bias[l4 + 256 * k];
      float v1 = macc[k][1] * inv[k] + bf2f(s4.y) + bias[l4 + 256 * k + 1];
      float v2 = macc[k][2] * inv[k] + bf2f(s4.z) + bias[l4 + 256 * k + 2];
      float v3 = macc[k][3] * inv[k] + bf2f(s4.w) + bias[l4 + 256 * k + 3];
      o.x = f2bf(v0 > 0.f ? v0 : expm1f(v0));
      o.y = f2bf(v1 > 0.f ? v1 : expm1f(v1));
      o.z = f2bf(v2 > 0.f ? v2 : expm1f(v2));
      o.w = f2bf(v3 > 0.f ? v3 : expm1f(v3));
      *(ushort4*)(xnext + (size_t)t * HF + l4 + 256 * k) = o;
    }
  } else {
    float4 o;
    float* op = &o.x;
#pragma unroll
    for (int c = 0; c < 4; ++c) {
      const float s3 = macc[0][c] * inv[0] + macc[1][c] * inv[1] + macc[2][c] * inv[2];
      const float tot = s3 + __shfl_xor(s3, 32, 64);
      op[c] = tot * (1.0f / 6.0f);
    }
    if (lane < 32) {
      const int f = lane * 4;
      const ushort4 s4 = *(const ushort4*)(Cb + (size_t)t * ncat + HF + f);
      o.x += bf2f(s4.x) + bias[f];
      o.y += bf2f(s4.y) + bias[f + 1];
      o.z += bf2f(s4.z) + bias[f + 2];
      o.w += bf2f(s4.w) + bias[f + 3];
      *(float4*)(outf + (size_t)t * FOUT + f) = o;
    }
  }
}

// ---------------- workspace layout ----------------
#define OFF_XBF 0ull
#define OFF_CB  92209152ull
#define OFF_WT  276627456ull   // scan partials alias it during CSR build
#define OFF_SS  279023616ull
#define OFF_ST  280463616ull
#define OFF_RP  287663616ull
#define OFF_CUR 287903744ull
#define OFF_ESR 288143872ull

extern "C" void kernel_launch(void* const* d_in, const int* in_sizes, int n_in,
                              void* d_out, int out_size, void* d_ws, size_t ws_size,
                              hipStream_t stream) {
  const float* x = (const float*)d_in[0];
  const int ei = (in_sizes[1] == 2 * EDGES) ? 1 : 16;
  const int base = (ei == 1) ? 2 : 1;
  const float *W[3], *AS[3], *AT[3], *SK[3], *B[3];
  for (int l = 0; l < 3; ++l) {
    W[l]  = (const float*)d_in[base + 5 * l + 0];
    AS[l] = (const float*)d_in[base + 5 * l + 1];
    AT[l] = (const float*)d_in[base + 5 * l + 2];
    SK[l] = (const float*)d_in[base + 5 * l + 3];
    B[l]  = (const float*)d_in[base + 5 * l + 4];
  }
  const int* edges = (const int*)d_in[ei];
  const int* srcv = edges;
  const int* tgtv = edges + EDGES;
  float* out = (float*)d_out;

  char* ws = (char*)d_ws;
  u16* xbf = (u16*)(ws + OFF_XBF);
  u16* Cb  = (u16*)(ws + OFF_CB);
  u16* WT  = (u16*)(ws + OFF_WT);
  int* partial = (int*)(ws + OFF_WT);    // aliases WT: live only during CSR build (before first prep)
  float* ss  = (float*)(ws + OFF_SS);
  float* stg = (float*)(ws + OFF_ST);
  int* rp  = (int*)(ws + OFF_RP);
  int* cur = (int*)(ws + OFF_CUR);
  int* esr = (int*)(ws + OFF_ESR);

  // CSR build
  hipMemsetAsync(cur, 0, NODES * sizeof(int), stream);
  hist_k<<<(EDGES + 255) / 256, 256, 0, stream>>>(tgtv, cur);
  scan1_k<<<SCAN_B, 1024, 0, stream>>>(cur, rp, partial);
  scan2_k<<<1, 64, 0, stream>>>(partial, rp + NODES);
  scan3_k<<<SCAN_B, 1024, 0, stream>>>(rp, partial, cur);
  scatter_k<<<(EDGES + 255) / 256, 256, 0, stream>>>(srcv, tgtv, cur, esr);

  convert_x_k<<<45024, 256, 0, stream>>>(x, xbf);

  for (int l = 0; l < 3; ++l) {
    const int nbx = (l < 2) ? 12 : 7;
    const int ncat = nbx * 128;
    if (l < 2)
      prep_wcat_k<0><<<dim3(48, 24), 256, 0, stream>>>(W[l], SK[l], WT);
    else
      prep_wcat_k<1><<<dim3(28, 24), 256, 0, stream>>>(W[l], SK[l], WT);
    gemm_k<<<nbx * 469, 256, 0, stream>>>(xbf, WT, Cb, AS[l], AT[l], ss, stg, nbx, ncat);
    if (l < 2)
      aggregate_k<0><<<15000, 256, 0, stream>>>(Cb, rp, esr, ss, stg, B[l], xbf, nullptr);
    else
      aggregate_k<1><<<15000, 256, 0, stream>>>(Cb, rp, esr, ss, stg, B[l], nullptr, out);
  }
}

// Round 10
// 839.854 us; speedup vs baseline: 1.3650x; 1.0444x over previous
//
#include <hip/hip_runtime.h>
#include <stdint.h>

#define NODES 60000
#define NPAD  60032   // 469 * 128
#define EDGES 240000
#define KDIM  768
#define HF    768     // HEADS * F_OUT
#define FOUT  128
#define SCAN_B 59     // ceil(NODES/1024)

typedef unsigned short u16;
typedef __bf16 bf16x8 __attribute__((ext_vector_type(8)));
typedef float f32x4 __attribute__((ext_vector_type(4)));

__device__ __forceinline__ float bf2f(u16 u) {
  union { uint32_t i; float f; } v; v.i = ((uint32_t)u) << 16; return v.f;
}
__device__ __forceinline__ u16 f2bf(float f) {
  union { float f; uint32_t i; } v; v.f = f;
  return (u16)((v.i + 0x7FFF + ((v.i >> 16) & 1)) >> 16);
}

// ---------------- convert x (f32 -> bf16, zero pad rows) ----------------
__global__ __launch_bounds__(256) void convert_x_k(const float* __restrict__ x, u16* __restrict__ xb) {
  const size_t g = ((size_t)blockIdx.x * 256 + threadIdx.x) * 4;
  if (g >= (size_t)NPAD * KDIM) return;
  ushort4 o;
  if (g < (size_t)NODES * KDIM) {
    const float4 v = *(const float4*)(x + g);
    o.x = f2bf(v.x); o.y = f2bf(v.y); o.z = f2bf(v.z); o.w = f2bf(v.w);
  } else { o.x = o.y = o.z = o.w = 0; }
  *(ushort4*)(xb + g) = o;
}

// ---------------- weight prep (LDS-tiled transpose) ----------------
// MODE 0: WT[n][k] = [W | skip][k][n], n<1536
// MODE 1: WT[n][k] = n<768 ? W[k][n] : mean_h skip[k][h*128 + (n-768)], n<896
template <int MODE>
__global__ __launch_bounds__(256) void prep_wcat_k(const float* __restrict__ W, const float* __restrict__ SK,
                                                   u16* __restrict__ WT) {
  __shared__ u16 tile[32][33];
  const int n0 = blockIdx.x * 32, k0 = blockIdx.y * 32;
  const int tx = threadIdx.x & 31, ty = threadIdx.x >> 5;  // 32 x 8
#pragma unroll
  for (int r = 0; r < 32; r += 8) {
    const int k = k0 + ty + r, n = n0 + tx;
    float v;
    if (n < HF) {
      v = W[(size_t)k * HF + n];
    } else if (MODE == 0) {
      v = SK[(size_t)k * HF + (n - HF)];
    } else {
      const int f = n - HF;
      v = 0.f;
#pragma unroll
      for (int h = 0; h < 6; ++h) v += SK[(size_t)k * HF + h * FOUT + f];
      v *= (1.0f / 6.0f);
    }
    tile[ty + r][tx] = f2bf(v);
  }
  __syncthreads();
#pragma unroll
  for (int r = 0; r < 32; r += 8) {
    const int n = n0 + ty + r, k = k0 + tx;
    WT[(size_t)n * KDIM + k] = tile[tx][ty + r];
  }
}

// ---------------- CSR build ----------------
__global__ __launch_bounds__(256) void hist_k(const int* __restrict__ tgt, int* __restrict__ deg) {
  const int e = blockIdx.x * 256 + threadIdx.x;
  if (e < EDGES) atomicAdd(&deg[tgt[e]], 1);
}

// 3-kernel coalesced scan: per-block Hillis-Steele -> scan block totals -> add offsets
__global__ __launch_bounds__(1024) void scan1_k(const int* __restrict__ deg, int* __restrict__ rp,
                                                int* __restrict__ partial) {
  __shared__ int buf[1024];
  const int tid = threadIdx.x;
  const int i = blockIdx.x * 1024 + tid;
  const int v = (i < NODES) ? deg[i] : 0;
  buf[tid] = v;
  __syncthreads();
  for (int off = 1; off < 1024; off <<= 1) {
    const int t = (tid >= off) ? buf[tid - off] : 0;
    __syncthreads();
    buf[tid] += t;
    __syncthreads();
  }
  if (i < NODES) rp[i] = buf[tid] - v;  // local exclusive
  if (tid == 1023) partial[blockIdx.x] = buf[1023];
}

__global__ __launch_bounds__(64) void scan2_k(int* __restrict__ partial, int* __restrict__ rpN) {
  __shared__ int buf[64];
  const int tid = threadIdx.x;
  const int v = (tid < SCAN_B) ? partial[tid] : 0;
  buf[tid] = v;
  __syncthreads();
  for (int off = 1; off < 64; off <<= 1) {
    const int t = (tid >= off) ? buf[tid - off] : 0;
    __syncthreads();
    buf[tid] += t;
    __syncthreads();
  }
  if (tid < SCAN_B) partial[tid] = buf[tid] - v;  // exclusive block offsets
  if (tid == 63) *rpN = buf[63];                  // total edge count
}

__global__ __launch_bounds__(1024) void scan3_k(int* __restrict__ rp, const int* __restrict__ partial,
                                                int* __restrict__ cur) {
  const int i = blockIdx.x * 1024 + threadIdx.x;
  if (i < NODES) {
    const int v = rp[i] + partial[blockIdx.x];
    rp[i] = v;
    cur[i] = v;
  }
}

__global__ __launch_bounds__(256) void scatter_k(const int* __restrict__ srcv, const int* __restrict__ tgt,
                                                 int* __restrict__ cur, int* __restrict__ esrc) {
  const int e = blockIdx.x * 256 + threadIdx.x;
  if (e < EDGES) {
    const int t = tgt[e];
    const int pos = atomicAdd(&cur[t], 1);
    esrc[pos] = srcv[e];
  }
}

// ---------------- bf16 MFMA GEMM + fused attention-score epilogue (R4-proven) ----------------
__global__ __launch_bounds__(256, 4) void gemm_k(const u16* __restrict__ A, const u16* __restrict__ BT,
                                                 u16* __restrict__ C,
                                                 const float* __restrict__ a_src, const float* __restrict__ a_tgt,
                                                 float* __restrict__ ss, float* __restrict__ stg,
                                                 int nbx, int ncat) {
  __shared__ u16 As[2][4096];
  __shared__ u16 Bs[2][4096];
  float* sp = (float*)&As[0][0];
  const int tid = threadIdx.x;
  const int lane = tid & 63;
  const int w = tid >> 6;
  const int wm = w >> 1, wn = w & 1;
  const int r16 = lane & 15, g4 = lane >> 4;

  const int NWG = nbx * 469;
  const int q = NWG >> 3, rr = NWG & 7;
  const int orig = blockIdx.x;
  const int xcd = orig & 7, idx = orig >> 3;
  const int wg = (xcd < rr ? xcd * (q + 1) : rr * (q + 1) + (xcd - rr) * q) + idx;
  const int bx = wg % nbx, by = wg / nbx;

  const size_t rowBase = (size_t)by * 128;
  const int colBase = bx * 128;

  const int c0 = tid, c1 = tid + 256;
  const size_t aoff0 = (rowBase + (c0 >> 2)) * KDIM + (c0 & 3) * 8;
  const size_t aoff1 = (rowBase + (c1 >> 2)) * KDIM + (c1 & 3) * 8;
  const size_t boff0 = ((size_t)(colBase + (c0 >> 2))) * KDIM + (c0 & 3) * 8;
  const size_t boff1 = ((size_t)(colBase + (c1 >> 2))) * KDIM + (c1 & 3) * 8;

  auto stage = [&](int buf, int k0) {
    __builtin_amdgcn_global_load_lds((__attribute__((address_space(1))) void*)(A + aoff0 + k0),
                                     (__attribute__((address_space(3))) void*)(&As[buf][w * 512]), 16, 0, 0);
    __builtin_amdgcn_global_load_lds((__attribute__((address_space(1))) void*)(A + aoff1 + k0),
                                     (__attribute__((address_space(3))) void*)(&As[buf][2048 + w * 512]), 16, 0, 0);
    __builtin_amdgcn_global_load_lds((__attribute__((address_space(1))) void*)(BT + boff0 + k0),
                                     (__attribute__((address_space(3))) void*)(&Bs[buf][w * 512]), 16, 0, 0);
    __builtin_amdgcn_global_load_lds((__attribute__((address_space(1))) void*)(BT + boff1 + k0),
                                     (__attribute__((address_space(3))) void*)(&Bs[buf][2048 + w * 512]), 16, 0, 0);
  };

  f32x4 acc[4][4];
#pragma unroll
  for (int i = 0; i < 4; ++i)
#pragma unroll
    for (int j = 0; j < 4; ++j) acc[i][j] = f32x4{0.f, 0.f, 0.f, 0.f};

  stage(0, 0);
  __syncthreads();
  for (int ks = 0; ks < 24; ++ks) {
    const int buf = ks & 1;
    if (ks < 23) stage(buf ^ 1, (ks + 1) * 32);
    bf16x8 af[4], bv[4];
#pragma unroll
    for (int i = 0; i < 4; ++i)
      af[i] = *(const bf16x8*)(&As[buf][(wm * 64 + i * 16 + r16) * 32 + g4 * 8]);
#pragma unroll
    for (int j = 0; j < 4; ++j)
      bv[j] = *(const bf16x8*)(&Bs[buf][(wn * 64 + j * 16 + r16) * 32 + g4 * 8]);
#pragma unroll
    for (int i = 0; i < 4; ++i)
#pragma unroll
      for (int j = 0; j < 4; ++j)
        acc[i][j] = __builtin_amdgcn_mfma_f32_16x16x32_bf16(af[i], bv[j], acc[i][j], 0, 0, 0);
    __syncthreads();
  }

#pragma unroll
  for (int i = 0; i < 4; ++i) {
    const size_t row0 = rowBase + wm * 64 + i * 16 + g4 * 4;
#pragma unroll
    for (int j = 0; j < 4; ++j) {
      const int col = colBase + wn * 64 + j * 16 + r16;
#pragma unroll
      for (int r = 0; r < 4; ++r)
        C[(row0 + r) * ncat + col] = f2bf(acc[i][j][r]);
    }
  }

  if (bx < 6) {
#pragma unroll
    for (int pass = 0; pass < 2; ++pass) {
      const float* av = (pass == 0) ? a_src : a_tgt;
      float a4[4];
#pragma unroll
      for (int j = 0; j < 4; ++j) a4[j] = av[bx * FOUT + wn * 64 + j * 16 + r16];
#pragma unroll
      for (int i = 0; i < 4; ++i) {
#pragma unroll
        for (int r = 0; r < 4; ++r) {
          float p = 0.f;
#pragma unroll
          for (int j = 0; j < 4; ++j) p += acc[i][j][r] * a4[j];
#pragma unroll
          for (int off = 1; off < 16; off <<= 1) p += __shfl_xor(p, off, 64);
          if (r16 == 0) {
            const int row = wm * 64 + i * 16 + g4 * 4 + r;
            sp[pass * 256 + wn * 128 + row] = p;
          }
        }
      }
    }
    __syncthreads();
    if (tid < 128) {
      const size_t row = rowBase + tid;
      if (row < NODES) {
        ss[row * 6 + bx] = sp[tid] + sp[128 + tid];
        stg[row * 6 + bx] = sp[256 + tid] + sp[384 + tid];
      }
    }
  }
}

// ---------------- fused ONLINE-softmax aggregation: one wave per target node, SINGLE edge pass ----------------
// lane covers cols {lane*4 + 256k + c : k<3, c<4}; head(col) = (lane>>5) + 2k
// Running (m,d,macc) per head; defer-max: rescale only when pair-max exceeds m+8 (ev bounded by e^8).
// macc/d is rescale-invariant -> identical math to two-pass softmax.
template <int MODE>
__global__ __launch_bounds__(256) void aggregate_k(const u16* __restrict__ Cb, const int* __restrict__ rp,
                                                   const int* __restrict__ esrc,
                                                   const float* __restrict__ ss, const float* __restrict__ stg,
                                                   const float* __restrict__ bias,
                                                   u16* __restrict__ xnext, float* __restrict__ outf) {
  constexpr int ncat = (MODE == 0) ? 1536 : 896;
  const int t = blockIdx.x * 4 + (threadIdx.x >> 6);
  const int lane = threadIdx.x & 63;
  if (t >= NODES) return;
  const int l4 = lane * 4;
  const int h0 = lane >> 5;

  const int b = rp[t], e = rp[t + 1];

  float sth[3], m[3], d[3], macc[3][4];
#pragma unroll
  for (int k = 0; k < 3; ++k) {
    sth[k] = stg[t * 6 + h0 + 2 * k];
    m[k] = -1e30f;
    d[k] = 0.f;
#pragma unroll
    for (int c = 0; c < 4; ++c) macc[k][c] = 0.f;
  }

  int j = b;
  for (; j + 1 < e; j += 2) {
    const int s0 = esrc[j], s1 = esrc[j + 1];
    const u16* pr0 = Cb + (size_t)s0 * ncat;
    const u16* pr1 = Cb + (size_t)s1 * ncat;
#pragma unroll
    for (int k = 0; k < 3; ++k) {
      const ushort4 v0 = *(const ushort4*)(pr0 + l4 + 256 * k);
      const ushort4 v1 = *(const ushort4*)(pr1 + l4 + 256 * k);
      float sc0 = ss[s0 * 6 + h0 + 2 * k] + sth[k];
      float sc1 = ss[s1 * 6 + h0 + 2 * k] + sth[k];
      sc0 = sc0 > 0.f ? sc0 : 0.2f * sc0;
      sc1 = sc1 > 0.f ? sc1 : 0.2f * sc1;
      const float pm = fmaxf(sc0, sc1);
      if (pm > m[k] + 8.f) {
        const float r = __expf(m[k] - pm);
        d[k] *= r;
        macc[k][0] *= r; macc[k][1] *= r; macc[k][2] *= r; macc[k][3] *= r;
        m[k] = pm;
      }
      const float ev0 = __expf(sc0 - m[k]);
      const float ev1 = __expf(sc1 - m[k]);
      d[k] += ev0 + ev1;
      macc[k][0] += ev0 * bf2f(v0.x) + ev1 * bf2f(v1.x);
      macc[k][1] += ev0 * bf2f(v0.y) + ev1 * bf2f(v1.y);
      macc[k][2] += ev0 * bf2f(v0.z) + ev1 * bf2f(v1.z);
      macc[k][3] += ev0 * bf2f(v0.w) + ev1 * bf2f(v1.w);
    }
  }
  if (j < e) {
    const int s0 = esrc[j];
    const u16* pr0 = Cb + (size_t)s0 * ncat;
#pragma unroll
    for (int k = 0; k < 3; ++k) {
      const ushort4 v0 = *(const ushort4*)(pr0 + l4 + 256 * k);
      float sc0 = ss[s0 * 6 + h0 + 2 * k] + sth[k];
      sc0 = sc0 > 0.f ? sc0 : 0.2f * sc0;
      if (sc0 > m[k] + 8.f) {
        const float r = __expf(m[k] - sc0);
        d[k] *= r;
        macc[k][0] *= r; macc[k][1] *= r; macc[k][2] *= r; macc[k][3] *= r;
        m[k] = sc0;
      }
      const float ev0 = __expf(sc0 - m[k]);
      d[k] += ev0;
      macc[k][0] += ev0 * bf2f(v0.x);
      macc[k][1] += ev0 * bf2f(v0.y);
      macc[k][2] += ev0 * bf2f(v0.z);
      macc[k][3] += ev0 * bf2f(v0.w);
    }
  }

  float inv[3];
#pragma unroll
  for (int k = 0; k < 3; ++k) inv[k] = 1.f / (d[k] + 1e-16f);

  if (MODE == 0) {
    const u16* sk = Cb + (size_t)t * ncat + HF;
#pragma unroll
    for (int k = 0; k < 3; ++k) {
      const ushort4 s4 = *(const ushort4*)(sk + l4 + 256 * k);
      ushort4 o;
      float v0 = macc[k][0] * inv[k] + bf2f(s4.x) + bias[l4 + 256 * k];
      float v1 = macc[k][1] * inv[k] + bf2f(s4.y) + bias[l4 + 256 * k + 1];
      float v2 = macc[k][2] * inv[k] + bf2f(s4.z) + bias[l4 + 256 * k + 2];
      float v3 = macc[k][3] * inv[k] + bf2f(s4.w) + bias[l4 + 256 * k + 3];
      o.x = f2bf(v0 > 0.f ? v0 : expm1f(v0));
      o.y = f2bf(v1 > 0.f ? v1 : expm1f(v1));
      o.z = f2bf(v2 > 0.f ? v2 : expm1f(v2));
      o.w = f2bf(v3 > 0.f ? v3 : expm1f(v3));
      *(ushort4*)(xnext + (size_t)t * HF + l4 + 256 * k) = o;
    }
  } else {
    float4 o;
    float* op = &o.x;
#pragma unroll
    for (int c = 0; c < 4; ++c) {
      const float s3 = macc[0][c] * inv[0] + macc[1][c] * inv[1] + macc[2][c] * inv[2];
      const float tot = s3 + __shfl_xor(s3, 32, 64);
      op[c] = tot * (1.0f / 6.0f);
    }
    if (lane < 32) {
      const int f = lane * 4;
      const ushort4 s4 = *(const ushort4*)(Cb + (size_t)t * ncat + HF + f);
      o.x += bf2f(s4.x) + bias[f];
      o.y += bf2f(s4.y) + bias[f + 1];
      o.z += bf2f(s4.z) + bias[f + 2];
      o.w += bf2f(s4.w) + bias[f + 3];
      *(float4*)(outf + (size_t)t * FOUT + f) = o;
    }
  }
}

// ---------------- workspace layout ----------------
#define OFF_XBF 0ull
#define OFF_CB  92209152ull
#define OFF_WT  276627456ull   // scan partials alias it during CSR build
#define OFF_SS  279023616ull
#define OFF_ST  280463616ull
#define OFF_RP  287663616ull
#define OFF_CUR 287903744ull
#define OFF_ESR 288143872ull

extern "C" void kernel_launch(void* const* d_in, const int* in_sizes, int n_in,
                              void* d_out, int out_size, void* d_ws, size_t ws_size,
                              hipStream_t stream) {
  const float* x = (const float*)d_in[0];
  const int ei = (in_sizes[1] == 2 * EDGES) ? 1 : 16;
  const int base = (ei == 1) ? 2 : 1;
  const float *W[3], *AS[3], *AT[3], *SK[3], *B[3];
  for (int l = 0; l < 3; ++l) {
    W[l]  = (const float*)d_in[base + 5 * l + 0];
    AS[l] = (const float*)d_in[base + 5 * l + 1];
    AT[l] = (const float*)d_in[base + 5 * l + 2];
    SK[l] = (const float*)d_in[base + 5 * l + 3];
    B[l]  = (const float*)d_in[base + 5 * l + 4];
  }
  const int* edges = (const int*)d_in[ei];
  const int* srcv = edges;
  const int* tgtv = edges + EDGES;
  float* out = (float*)d_out;

  char* ws = (char*)d_ws;
  u16* xbf = (u16*)(ws + OFF_XBF);
  u16* Cb  = (u16*)(ws + OFF_CB);
  u16* WT  = (u16*)(ws + OFF_WT);
  int* partial = (int*)(ws + OFF_WT);    // aliases WT: live only during CSR build (before first prep)
  float* ss  = (float*)(ws + OFF_SS);
  float* stg = (float*)(ws + OFF_ST);
  int* rp  = (int*)(ws + OFF_RP);
  int* cur = (int*)(ws + OFF_CUR);
  int* esr = (int*)(ws + OFF_ESR);

  // CSR build
  hipMemsetAsync(cur, 0, NODES * sizeof(int), stream);
  hist_k<<<(EDGES + 255) / 256, 256, 0, stream>>>(tgtv, cur);
  scan1_k<<<SCAN_B, 1024, 0, stream>>>(cur, rp, partial);
  scan2_k<<<1, 64, 0, stream>>>(partial, rp + NODES);
  scan3_k<<<SCAN_B, 1024, 0, stream>>>(rp, partial, cur);
  scatter_k<<<(EDGES + 255) / 256, 256, 0, stream>>>(srcv, tgtv, cur, esr);

  convert_x_k<<<45024, 256, 0, stream>>>(x, xbf);

  for (int l = 0; l < 3; ++l) {
    const int nbx = (l < 2) ? 12 : 7;
    const int ncat = nbx * 128;
    if (l < 2)
      prep_wcat_k<0><<<dim3(48, 24), 256, 0, stream>>>(W[l], SK[l], WT);
    else
      prep_wcat_k<1><<<dim3(28, 24), 256, 0, stream>>>(W[l], SK[l], WT);
    gemm_k<<<nbx * 469, 256, 0, stream>>>(xbf, WT, Cb, AS[l], AT[l], ss, stg, nbx, ncat);
    if (l < 2)
      aggregate_k<0><<<15000, 256, 0, stream>>>(Cb, rp, esr, ss, stg, B[l], xbf, nullptr);
    else
      aggregate_k<1><<<15000, 256, 0, stream>>>(Cb, rp, esr, ss, stg, B[l], nullptr, out);
  }
}